// Round 11
// baseline (120.996 us; speedup 1.0000x reference)
//
#include <hip/hip_runtime.h>

// ---------------------------------------------------------------------------
// AttentionPairBias on MI355X (gfx950).
//   1. gw_prep (1 block): gwT = ln_g*wz fp16, G, bw
//   2. mega (1 launch, role-disjoint, NO gl_lds anywhere):
//        blocks 0..1023    conv s,k_in fp32->fp16
//        blocks 1024..2303 convT wq..wo fp32(K,N)->fp16(N,K)
//        blocks 2304..10495 ln_bias slim (reg A-frags, shfl stats) -> bias16
//      (conv/convT BW hides under ln's 268 MB window)
//   3. gemm_fused grid(256,4): 64^2 tiles (4 blocks/CU), BK=64 dbuf,
//      gload_lds + src-XOR swizzle: q=(s@wq+bq)/8, k, g=sigmoid(s@wg);
//      mode 2 writes vT directly (fused transpose via LDS roundtrip)
//   4. flash: swapped QK^T with direct global bias/mask C-init, in-register
//      softmax, fp16 P pack, shfl-redistribute, PV MFMA, x16 = fp16(g*o)
//   5. gemm_o: 64x32 tiles, 512 blocks: out = x@wo (fp32)
// ---------------------------------------------------------------------------

typedef _Float16 h8 __attribute__((ext_vector_type(8)));
typedef _Float16 h4 __attribute__((ext_vector_type(4)));
typedef float f32x4 __attribute__((ext_vector_type(4)));
typedef unsigned int u32;

#define MFMA16(a, b, c) __builtin_amdgcn_mfma_f32_16x16x32_f16(a, b, c, 0, 0, 0)

__device__ __forceinline__ u32 pkrtz(float a, float b) {
  return __builtin_bit_cast(u32, __builtin_amdgcn_cvt_pkrtz(a, b));
}

__device__ __forceinline__ void gl_lds16(const void* g, void* l) {
  __builtin_amdgcn_global_load_lds(
      (const __attribute__((address_space(1))) u32*)g,
      (__attribute__((address_space(3))) u32*)l, 16, 0, 0);
}

// workspace layout (bytes)
static constexpr size_t OFF_S16   = 0;          // 1M fp16
static constexpr size_t OFF_KIN16 = 2097152;
static constexpr size_t OFF_WQT   = 4194304;
static constexpr size_t OFF_WKT   = 6291456;
static constexpr size_t OFF_WVT   = 8388608;
static constexpr size_t OFF_WGT   = 10485760;
static constexpr size_t OFF_WOT   = 12582912;
static constexpr size_t OFF_Q16   = 14680064;
static constexpr size_t OFF_K16   = 16777216;
static constexpr size_t OFF_VT16  = 20971520;
static constexpr size_t OFF_X16   = 23068672;
static constexpr size_t OFF_G32   = 25165824;   // 1M fp32
static constexpr size_t OFF_GWT   = 29360128;   // 16x128 fp16
static constexpr size_t OFF_GBW   = 29368320;   // 32 fp32
static constexpr size_t OFF_BIAS  = 33554432;   // 16 MiB fp16

// --------------------------- gw prep (1 block) ------------------------------
__global__ __launch_bounds__(256) void gw_prep_kernel(
    const float* __restrict__ lng, const float* __restrict__ lnb,
    const float* __restrict__ wz, _Float16* __restrict__ gwT,
    float* __restrict__ Gbw) {
  int t = threadIdx.x;
  __shared__ float red[2][16][16];
  int h = t & 15, cg = t >> 4;
  float pg = 0.f, pb = 0.f;
#pragma unroll
  for (int u = 0; u < 8; ++u) {
    int c = cg * 8 + u;
    float w = wz[c * 16 + h];
    _Float16 gh = (_Float16)(lng[c] * w);
    gwT[h * 128 + c] = gh;
    pg += (float)gh;
    pb += lnb[c] * w;
  }
  red[0][h][cg] = pg; red[1][h][cg] = pb;
  __syncthreads();
  if (t < 32) {
    int hh = t & 15, which = t >> 4;
    float ssum = 0.f;
#pragma unroll
    for (int u = 0; u < 16; ++u) ssum += red[which][hh][u];
    Gbw[which * 16 + hh] = ssum;
  }
}

// -------- mega: conv (0..1023) | convT (1024..2303) | ln (2304..10495) ------
__global__ __launch_bounds__(256) void mega_kernel(
    const float* __restrict__ s, const float* __restrict__ kin,
    _Float16* __restrict__ s16, _Float16* __restrict__ kin16,
    const float* __restrict__ w0, const float* __restrict__ w1,
    const float* __restrict__ w2, const float* __restrict__ w3,
    const float* __restrict__ w4,
    _Float16* __restrict__ o0, _Float16* __restrict__ o1,
    _Float16* __restrict__ o2, _Float16* __restrict__ o3,
    _Float16* __restrict__ o4,
    const float* __restrict__ z, const _Float16* __restrict__ gwT,
    const float* __restrict__ Gbw, _Float16* __restrict__ bias16) {
  __shared__ __align__(16) char smem[9216];
  int bid = blockIdx.x, t = threadIdx.x;
  if (bid < 1024) {  // ---------------- conv role ---------------------------
    const float* in = (bid < 512) ? s : kin;
    _Float16* out = (bid < 512) ? s16 : kin16;
    int i = (bid & 511) * 256 + t;
    const float4* p = (const float4*)in + (size_t)i * 2;
    float4 a = p[0], b = p[1];
    h8 v;
    v[0] = (_Float16)a.x; v[1] = (_Float16)a.y; v[2] = (_Float16)a.z; v[3] = (_Float16)a.w;
    v[4] = (_Float16)b.x; v[5] = (_Float16)b.y; v[6] = (_Float16)b.z; v[7] = (_Float16)b.w;
    *(h8*)(out + (size_t)i * 8) = v;
    return;
  }
  if (bid < 2304) {  // ---------------- convT role --------------------------
    int r5 = bid - 1024;
    int y = r5 >> 8, tile = r5 & 255;
    const float* w; _Float16* o;
    switch (y) {
      case 0: w = w0; o = o0; break;
      case 1: w = w1; o = o1; break;
      case 2: w = w2; o = o2; break;
      case 3: w = w3; o = o3; break;
      default: w = w4; o = o4; break;
    }
    int tr = tile >> 4, tc = tile & 15;
    _Float16 (*ts)[72] = (_Float16(*)[72])smem;
#pragma unroll
    for (int p = 0; p < 4; ++p) {
      int e = p * 1024 + t * 4;
      int r = e >> 6, c = e & 63;
      float4 v = *(const float4*)(w + (size_t)(tr * 64 + r) * 1024 + tc * 64 + c);
      h4 hv;
      hv[0] = (_Float16)v.x; hv[1] = (_Float16)v.y; hv[2] = (_Float16)v.z; hv[3] = (_Float16)v.w;
      *(h4*)&ts[r][c] = hv;
    }
    __syncthreads();
#pragma unroll
    for (int p = 0; p < 4; ++p) {
      int e = p * 1024 + t * 4;
      int n = e >> 6, k = e & 63;
      h4 hv;
#pragma unroll
      for (int u = 0; u < 4; ++u) hv[u] = ts[k + u][n];
      *(h4*)(o + (size_t)(tc * 64 + n) * 1024 + tr * 64 + k) = hv;
    }
    return;
  }
  // ------------------------------ LN role -----------------------------------
  int r6 = bid - 2304;
  int jc = r6 & 7, i = (r6 >> 3) & 511, b = r6 >> 12;
  float (*outs)[17] = (float(*)[17])smem;   // 4352 B
  int wid = t >> 6, lane = t & 63;
  int lr = lane & 15, hi = lane >> 4;
  const float* zr = z + (((size_t)b * 512 + i) * 512 + (size_t)jc * 64 + wid * 16 + lr) * 128;
  h8 af[4];
  float s1 = 0.f, s2 = 0.f;
#pragma unroll
  for (int kk = 0; kk < 4; ++kk) {
    float4 v0 = *(const float4*)(zr + kk * 32 + hi * 8);
    float4 v1 = *(const float4*)(zr + kk * 32 + hi * 8 + 4);
    s1 += v0.x + v0.y + v0.z + v0.w + v1.x + v1.y + v1.z + v1.w;
    s2 += v0.x * v0.x + v0.y * v0.y + v0.z * v0.z + v0.w * v0.w +
          v1.x * v1.x + v1.y * v1.y + v1.z * v1.z + v1.w * v1.w;
    h8 a;
    a[0] = (_Float16)v0.x; a[1] = (_Float16)v0.y; a[2] = (_Float16)v0.z; a[3] = (_Float16)v0.w;
    a[4] = (_Float16)v1.x; a[5] = (_Float16)v1.y; a[6] = (_Float16)v1.z; a[7] = (_Float16)v1.w;
    af[kk] = a;
  }
  s1 += __shfl_xor(s1, 16, 64); s2 += __shfl_xor(s2, 16, 64);
  s1 += __shfl_xor(s1, 32, 64); s2 += __shfl_xor(s2, 32, 64);
  float mu = s1 * (1.0f / 128.0f);
  float var = s2 * (1.0f / 128.0f) - mu * mu;
  float rs = rsqrtf(var + 1e-5f);
  f32x4 acc = {};
#pragma unroll
  for (int kk = 0; kk < 4; ++kk) {
    h8 bf = *(const h8*)(gwT + lr * 128 + kk * 32 + hi * 8);
    acc = MFMA16(af[kk], bf, acc);
  }
  float Gl = Gbw[lr], bwl = Gbw[16 + lr];
#pragma unroll
  for (int r = 0; r < 4; ++r) {
    int src = hi * 4 + r;
    float mur = __shfl(mu, src, 64);
    float rsr = __shfl(rs, src, 64);
    outs[wid * 16 + src][lr] = rsr * (acc[r] - mur * Gl) + bwl;
  }
  __syncthreads();
  {
    int hh = t >> 4, j0w = (t & 15) * 4;
    h4 ov;
    ov[0] = (_Float16)outs[j0w + 0][hh]; ov[1] = (_Float16)outs[j0w + 1][hh];
    ov[2] = (_Float16)outs[j0w + 2][hh]; ov[3] = (_Float16)outs[j0w + 3][hh];
    *(h4*)(bias16 + (((size_t)(b * 16 + hh) * 512) + i) * 512 + (size_t)jc * 64 + j0w) = ov;
  }
}

// -------- fused 1024^3 GEMMs: 64^2 tiles (4 blocks/CU), BK=64, gload_lds ----
// mode 0: q=(s@wq+bq)/8  1: k=kin@wk  2: vT (transposed write)  3: g=sigmoid
__global__ __launch_bounds__(256) void gemm_fused(
    const _Float16* __restrict__ s16, const _Float16* __restrict__ kin16,
    const _Float16* __restrict__ wqT, const _Float16* __restrict__ wkT,
    const _Float16* __restrict__ wvT, const _Float16* __restrict__ wgT,
    const float* __restrict__ bq,
    _Float16* __restrict__ q16, _Float16* __restrict__ k16,
    _Float16* __restrict__ vT, float* __restrict__ g32) {
  int mode = blockIdx.y;
  const _Float16 *A, *BT;
  switch (mode) {
    case 0: A = s16;   BT = wqT; break;
    case 1: A = kin16; BT = wkT; break;
    case 2: A = kin16; BT = wvT; break;
    default: A = s16;  BT = wgT; break;
  }
  int bm = blockIdx.x >> 4, bn = blockIdx.x & 15;
  __shared__ _Float16 As[2][64 * 64];
  __shared__ _Float16 Bs[2][64 * 64];
  int t = threadIdx.x, wid = t >> 6, lane = t & 63;
  int wr = wid >> 1, wc = wid & 1, lr = lane & 15, hi = lane >> 4;
  const _Float16* Ab = A + (size_t)(bm * 64) * 1024;
  const _Float16* Bb = BT + (size_t)(bn * 64) * 1024;
  auto STAGE = [&](int kt, int buf) {
    int k0 = kt * 64;
#pragma unroll
    for (int p = 0; p < 2; ++p) {
      int q = (wid * 2 + p) * 64 + lane;   // 16B-unit 0..511, 8 per row
      int row = q >> 3, c16 = q & 7;
      int coff = (c16 * 16) ^ ((row & 7) << 4);
      gl_lds16(Ab + (size_t)row * 1024 + k0 + (coff >> 1),
               (char*)As[buf] + (wid * 2 + p) * 1024);
      gl_lds16(Bb + (size_t)row * 1024 + k0 + (coff >> 1),
               (char*)Bs[buf] + (wid * 2 + p) * 1024);
    }
  };
  f32x4 acc[2][2] = {};
  STAGE(0, 0);
  __syncthreads();
  for (int kt = 0; kt < 16; ++kt) {
    int buf = kt & 1;
    if (kt < 15) STAGE(kt + 1, buf ^ 1);
#pragma unroll
    for (int kk = 0; kk < 2; ++kk) {
      h8 af[2], bf[2];
#pragma unroll
      for (int mi = 0; mi < 2; ++mi) {
        int row = wr * 32 + mi * 16 + lr;
        af[mi] = *(const h8*)((char*)As[buf] + row * 128 + ((kk * 64 + hi * 16) ^ ((lr & 7) << 4)));
      }
#pragma unroll
      for (int ni = 0; ni < 2; ++ni) {
        int row = wc * 32 + ni * 16 + lr;
        bf[ni] = *(const h8*)((char*)Bs[buf] + row * 128 + ((kk * 64 + hi * 16) ^ ((lr & 7) << 4)));
      }
#pragma unroll
      for (int mi = 0; mi < 2; ++mi)
#pragma unroll
        for (int ni = 0; ni < 2; ++ni)
          acc[mi][ni] = MFMA16(af[mi], bf[ni], acc[mi][ni]);
    }
    __syncthreads();
  }

  if (mode == 2) {
    // fused transpose: tile = 64 tokens x head bn (64 d); b = bm>>3.
    _Float16 (*ts)[72] = (_Float16(*)[72])As;   // after final barrier
#pragma unroll
    for (int mi = 0; mi < 2; ++mi)
#pragma unroll
      for (int ni = 0; ni < 2; ++ni)
#pragma unroll
        for (int r = 0; r < 4; ++r) {
          int tok = wr * 32 + mi * 16 + hi * 4 + r;
          int d = wc * 32 + ni * 16 + lr;
          ts[tok][d ^ (((tok >> 3) & 7) << 3)] = (_Float16)acc[mi][ni][r];
        }
    __syncthreads();
    int b = bm >> 3;
    _Float16* vtb = vT + ((size_t)(b * 16 + bn) * 64) * 512 + (bm & 7) * 64;
#pragma unroll
    for (int p = 0; p < 2; ++p) {
      int d = p * 32 + (t >> 3), j0 = (t & 7) * 8;
      h8 v;
#pragma unroll
      for (int u = 0; u < 8; ++u) {
        int j = j0 + u;
        v[u] = ts[j][d ^ (((j >> 3) & 7) << 3)];
      }
      *(h8*)(vtb + (size_t)d * 512 + j0) = v;
    }
    return;
  }

#pragma unroll
  for (int mi = 0; mi < 2; ++mi)
#pragma unroll
    for (int ni = 0; ni < 2; ++ni)
#pragma unroll
      for (int r = 0; r < 4; ++r) {
        int row = bm * 64 + wr * 32 + mi * 16 + hi * 4 + r;
        int col = bn * 64 + wc * 32 + ni * 16 + lr;
        float v = acc[mi][ni][r];
        size_t o = (size_t)row * 1024 + col;
        switch (mode) {
          case 0: q16[o] = (_Float16)((v + bq[col]) * 0.125f); break;
          case 1: k16[o] = (_Float16)v; break;
          default: g32[o] = 1.0f / (1.0f + __expf(-v)); break;
        }
      }
}

// ----------------- fused attention: QK^T+bias -> softmax -> PV -> gate ------
__global__ __launch_bounds__(256, 2) void flash_kernel(
    const _Float16* __restrict__ q16, const _Float16* __restrict__ k16,
    const _Float16* __restrict__ vT, const _Float16* __restrict__ bias16,
    const float* __restrict__ mask, const float* __restrict__ g32,
    _Float16* __restrict__ x16) {
  int bh = blockIdx.y, b = bh >> 4, h = bh & 15;
  int i0 = blockIdx.x * 64;
  __shared__ _Float16 Kc[2][128 * 64];   // K chunks (phase1) / vT chunks (phase2)
  int t = threadIdx.x, wid = t >> 6, lane = t & 63;
  int lr = lane & 15, hi = lane >> 4;

  const _Float16* qrow = q16 + ((size_t)(b * 512) + i0 + wid * 16 + lr) * 1024 + h * 64;
  h8 qf0 = *(const h8*)(qrow + hi * 8);
  h8 qf1 = *(const h8*)(qrow + 32 + hi * 8);

  const _Float16* bbase = bias16 + ((size_t)bh * 512 + i0 + wid * 16 + lr) * 512 + hi * 4;
  const float* mbase = mask + b * 512 + hi * 4;

  auto STAGE1 = [&](int c, int buf) {
    int j0 = c * 128;
    const _Float16* kb = k16 + ((size_t)(b * 512) + j0) * 1024 + h * 64;
#pragma unroll
    for (int p = 0; p < 4; ++p) {
      int q = (wid * 4 + p) * 64 + lane;
      int row = q >> 3, c16 = q & 7;
      int coff = (c16 * 16) ^ ((row & 7) << 4);
      gl_lds16(kb + (size_t)row * 1024 + (coff >> 1),
               (char*)Kc[buf] + (wid * 4 + p) * 1024);
    }
  };

  f32x4 acc[32];
  STAGE1(0, 0);
  __syncthreads();
#pragma unroll
  for (int c = 0; c < 4; ++c) {
    int buf = c & 1;
    if (c < 3) STAGE1(c + 1, buf ^ 1);
#pragma unroll
    for (int jtl = 0; jtl < 8; ++jtl) {
      int jt = c * 8 + jtl;
      int krow = jtl * 16 + lr;
      h8 kf0 = *(const h8*)((char*)Kc[buf] + krow * 128 + ((hi * 16) ^ ((lr & 7) << 4)));
      h8 kf1 = *(const h8*)((char*)Kc[buf] + krow * 128 + ((64 + hi * 16) ^ ((lr & 7) << 4)));
      h4 bv = *(const h4*)(bbase + jt * 16);
      float4 mv = *(const float4*)(mbase + jt * 16);
      f32x4 a;
      a[0] = (float)bv[0] + (1.0f - mv.x) * -1000000.0f;
      a[1] = (float)bv[1] + (1.0f - mv.y) * -1000000.0f;
      a[2] = (float)bv[2] + (1.0f - mv.z) * -1000000.0f;
      a[3] = (float)bv[3] + (1.0f - mv.w) * -1000000.0f;
      a = MFMA16(kf0, qf0, a);
      a = MFMA16(kf1, qf1, a);
      acc[jt] = a;
    }
    __syncthreads();
  }

  float m = -3.4e38f;
#pragma unroll
  for (int jt = 0; jt < 32; ++jt)
    m = fmaxf(m, fmaxf(fmaxf(acc[jt][0], acc[jt][1]), fmaxf(acc[jt][2], acc[jt][3])));
  m = fmaxf(m, __shfl_xor(m, 16, 64));
  m = fmaxf(m, __shfl_xor(m, 32, 64));
  float ssum = 0.f;
#pragma unroll
  for (int jt = 0; jt < 32; ++jt) {
#pragma unroll
    for (int r = 0; r < 4; ++r) {
      float e = __expf(acc[jt][r] - m);
      acc[jt][r] = e;
      ssum += e;
    }
  }
  ssum += __shfl_xor(ssum, 16, 64);
  ssum += __shfl_xor(ssum, 32, 64);
  float inv = 1.0f / ssum;
  u32 pk0[32], pk1[32];
#pragma unroll
  for (int jt = 0; jt < 32; ++jt) {
    pk0[jt] = pkrtz(acc[jt][0] * inv, acc[jt][1] * inv);
    pk1[jt] = pkrtz(acc[jt][2] * inv, acc[jt][3] * inv);
  }

  auto STAGE2 = [&](int c, int buf) {
    int j0 = c * 128;
    const _Float16* vb = vT + ((size_t)bh * 64) * 512 + j0;
#pragma unroll
    for (int p = 0; p < 4; ++p) {
      int q = (wid * 4 + p) * 64 + lane;
      int row = q >> 4, c16 = q & 15;
      int coff = (c16 * 16) ^ ((row & 7) << 4);
      gl_lds16(vb + (size_t)row * 512 + (coff >> 1),
               (char*)Kc[buf] + (wid * 4 + p) * 1024);
    }
  };
  f32x4 oacc[4] = {};
  STAGE2(0, 0);
  __syncthreads();
#pragma unroll
  for (int c = 0; c < 4; ++c) {
    int buf = c & 1;
    if (c < 3) STAGE2(c + 1, buf ^ 1);
#pragma unroll
    for (int ktl = 0; ktl < 4; ++ktl) {
      int kt = c * 4 + ktl;
      int la = lr + ((hi & 1) << 5);
      int lb = la + 16;
      u32 a0 = __shfl(pk0[2 * kt], la, 64);
      u32 a1 = __shfl(pk1[2 * kt], la, 64);
      u32 b0 = __shfl(pk0[2 * kt], lb, 64);
      u32 b1 = __shfl(pk1[2 * kt], lb, 64);
      u32 c0 = __shfl(pk0[2 * kt + 1], la, 64);
      u32 c1 = __shfl(pk1[2 * kt + 1], la, 64);
      u32 d0 = __shfl(pk0[2 * kt + 1], lb, 64);
      u32 d1 = __shfl(pk1[2 * kt + 1], lb, 64);
      bool x1 = hi >= 2;
      uint4 au;
      au.x = x1 ? c0 : a0;
      au.y = x1 ? c1 : a1;
      au.z = x1 ? d0 : b0;
      au.w = x1 ? d1 : b1;
      h8 paf = __builtin_bit_cast(h8, au);
#pragma unroll
      for (int nt = 0; nt < 4; ++nt) {
        int vrow = nt * 16 + lr;
        h8 vf = *(const h8*)((char*)Kc[buf] + vrow * 256 + ((ktl * 64 + hi * 16) ^ ((lr & 7) << 4)));
        oacc[nt] = MFMA16(paf, vf, oacc[nt]);
      }
    }
    __syncthreads();
  }

  const float* gb = g32 + ((size_t)(b * 512) + i0) * 1024 + h * 64;
  _Float16* xb = x16 + ((size_t)(b * 512) + i0) * 1024 + h * 64;
#pragma unroll
  for (int nt = 0; nt < 4; ++nt)
#pragma unroll
    for (int r = 0; r < 4; ++r) {
      int il = wid * 16 + hi * 4 + r, d = nt * 16 + lr;
      size_t off = (size_t)il * 1024 + d;
      xb[off] = (_Float16)(oacc[nt][r] * gb[off]);
    }
}

// --------- out = x @ wo, 64x32 tiles (512 blocks, 2/CU), BK=64 --------------
__global__ __launch_bounds__(256) void gemm_o_kernel(
    const _Float16* __restrict__ x16, const _Float16* __restrict__ woT,
    float* __restrict__ out32) {
  int bm = blockIdx.x >> 5, bn = blockIdx.x & 31;   // 16 x 32
  __shared__ _Float16 As[2][64 * 64];
  __shared__ _Float16 Bs[2][32 * 64];
  int t = threadIdx.x, wid = t >> 6, lane = t & 63;
  int wr = wid >> 1, wc = wid & 1, lr = lane & 15, hi = lane >> 4;
  const _Float16* Ab = x16 + (size_t)(bm * 64) * 1024;
  const _Float16* Bb = woT + (size_t)(bn * 32) * 1024;
  auto STAGE = [&](int kt, int buf) {
    int k0 = kt * 64;
#pragma unroll
    for (int p = 0; p < 2; ++p) {
      int q = (wid * 2 + p) * 64 + lane;   // A: 512 units
      int row = q >> 3, c16 = q & 7;
      int coff = (c16 * 16) ^ ((row & 7) << 4);
      gl_lds16(Ab + (size_t)row * 1024 + k0 + (coff >> 1),
               (char*)As[buf] + (wid * 2 + p) * 1024);
    }
    {
      int q = t;                            // B: 256 units
      int row = q >> 3, c16 = q & 7;
      int coff = (c16 * 16) ^ ((row & 7) << 4);
      gl_lds16(Bb + (size_t)row * 1024 + k0 + (coff >> 1),
               (char*)Bs[buf] + wid * 1024);
    }
  };
  f32x4 acc[2] = {};
  STAGE(0, 0);
  __syncthreads();
  for (int kt = 0; kt < 16; ++kt) {
    int buf = kt & 1;
    if (kt < 15) STAGE(kt + 1, buf ^ 1);
#pragma unroll
    for (int kk = 0; kk < 2; ++kk) {
      h8 af[2], bf;
#pragma unroll
      for (int mi = 0; mi < 2; ++mi) {
        int row = wr * 32 + mi * 16 + lr;
        af[mi] = *(const h8*)((char*)As[buf] + row * 128 + ((kk * 64 + hi * 16) ^ ((lr & 7) << 4)));
      }
      {
        int row = wc * 16 + lr;
        bf = *(const h8*)((char*)Bs[buf] + row * 128 + ((kk * 64 + hi * 16) ^ ((lr & 7) << 4)));
      }
#pragma unroll
      for (int mi = 0; mi < 2; ++mi)
        acc[mi] = MFMA16(af[mi], bf, acc[mi]);
    }
    __syncthreads();
  }
#pragma unroll
  for (int mi = 0; mi < 2; ++mi)
#pragma unroll
    for (int r = 0; r < 4; ++r) {
      int row = bm * 64 + wr * 32 + mi * 16 + hi * 4 + r;
      int col = bn * 32 + wc * 16 + lr;
      out32[(size_t)row * 1024 + col] = acc[mi][r];
    }
}

// ----------------------------------------------------------------------------
extern "C" void kernel_launch(void* const* d_in, const int* in_sizes, int n_in,
                              void* d_out, int out_size, void* d_ws, size_t ws_size,
                              hipStream_t stream) {
  const float* s    = (const float*)d_in[0];
  const float* z    = (const float*)d_in[1];
  const float* mask = (const float*)d_in[2];
  const float* kin  = (const float*)d_in[3];
  const float* wq   = (const float*)d_in[4];
  const float* bq   = (const float*)d_in[5];
  const float* wk   = (const float*)d_in[6];
  const float* wv   = (const float*)d_in[7];
  const float* wg   = (const float*)d_in[8];
  const float* lng  = (const float*)d_in[9];
  const float* lnb  = (const float*)d_in[10];
  const float* wz   = (const float*)d_in[11];
  const float* wo   = (const float*)d_in[12];
  float* out = (float*)d_out;

  char* ws = (char*)d_ws;
  _Float16* s16   = (_Float16*)(ws + OFF_S16);
  _Float16* kin16 = (_Float16*)(ws + OFF_KIN16);
  _Float16* wqT   = (_Float16*)(ws + OFF_WQT);
  _Float16* wkT   = (_Float16*)(ws + OFF_WKT);
  _Float16* wvT   = (_Float16*)(ws + OFF_WVT);
  _Float16* wgT   = (_Float16*)(ws + OFF_WGT);
  _Float16* woT   = (_Float16*)(ws + OFF_WOT);
  _Float16* q16   = (_Float16*)(ws + OFF_Q16);
  _Float16* k16   = (_Float16*)(ws + OFF_K16);
  _Float16* vT16  = (_Float16*)(ws + OFF_VT16);
  _Float16* x16   = (_Float16*)(ws + OFF_X16);
  float* g32      = (float*)(ws + OFF_G32);
  _Float16* gwT   = (_Float16*)(ws + OFF_GWT);
  float* Gbw      = (float*)(ws + OFF_GBW);
  _Float16* bias16= (_Float16*)(ws + OFF_BIAS);

  gw_prep_kernel<<<1, 256, 0, stream>>>(lng, lnb, wz, gwT, Gbw);
  mega_kernel<<<10496, 256, 0, stream>>>(s, kin, s16, kin16,
                                         wq, wk, wv, wg, wo,
                                         wqT, wkT, wvT, wgT, woT,
                                         z, gwT, Gbw, bias16);
  gemm_fused<<<dim3(256, 4), 256, 0, stream>>>(s16, kin16, wqT, wkT, wvT, wgT,
                                               bq, q16, k16, vT16, g32);
  flash_kernel<<<dim3(8, 32), 256, 0, stream>>>(q16, k16, vT16, bias16,
                                                mask, g32, x16);
  gemm_o_kernel<<<512, 256, 0, stream>>>(x16, woT, out);
}

// Round 12
// 117.570 us; speedup vs baseline: 1.0291x; 1.0291x over previous
//
#include <hip/hip_runtime.h>

// ---------------------------------------------------------------------------
// AttentionPairBias on MI355X (gfx950).  [R10 best configuration — verbatim]
//   1. prep (1 launch): conv s,k_in fp32->fp16 | convT wq..wo -> fp16(N,K) |
//      gw prep (gwT = ln_g*wz fp16, G, bw)
//   2. ln_bias slim: reg A-frags, shfl stats -> bias16[b,h,i,j] fp16
//      (separate dispatch; co-dispatch with GEMM fails — R5/R7)
//   3. gemm_fused grid(256,4): 64^2 tiles (4 blocks/CU), BK=64 dbuf,
//      gload_lds + src-XOR swizzle: q=(s@wq+bq)/8, k, g=sigmoid(s@wg);
//      mode 2 writes vT DIRECTLY (fused transpose via LDS roundtrip)
//   4. flash (2 blocks/CU): swapped QK^T with direct global bias/mask C-init,
//      in-register softmax, fp16 P pack, shfl-redistribute, PV MFMA,
//      epilogue x16 = fp16(g*o). LDS 32 KB.
//   5. gemm_o: 64x32 tiles, 512 blocks: out = x@wo (fp32)
// ---------------------------------------------------------------------------

typedef _Float16 h8 __attribute__((ext_vector_type(8)));
typedef _Float16 h4 __attribute__((ext_vector_type(4)));
typedef float f32x4 __attribute__((ext_vector_type(4)));
typedef unsigned int u32;

#define MFMA16(a, b, c) __builtin_amdgcn_mfma_f32_16x16x32_f16(a, b, c, 0, 0, 0)

__device__ __forceinline__ u32 pkrtz(float a, float b) {
  return __builtin_bit_cast(u32, __builtin_amdgcn_cvt_pkrtz(a, b));
}

__device__ __forceinline__ void gl_lds16(const void* g, void* l) {
  __builtin_amdgcn_global_load_lds(
      (const __attribute__((address_space(1))) u32*)g,
      (__attribute__((address_space(3))) u32*)l, 16, 0, 0);
}

// workspace layout (bytes)
static constexpr size_t OFF_S16   = 0;          // 1M fp16
static constexpr size_t OFF_KIN16 = 2097152;
static constexpr size_t OFF_WQT   = 4194304;
static constexpr size_t OFF_WKT   = 6291456;
static constexpr size_t OFF_WVT   = 8388608;
static constexpr size_t OFF_WGT   = 10485760;
static constexpr size_t OFF_WOT   = 12582912;
static constexpr size_t OFF_Q16   = 14680064;
static constexpr size_t OFF_K16   = 16777216;
static constexpr size_t OFF_VT16  = 20971520;
static constexpr size_t OFF_X16   = 23068672;
static constexpr size_t OFF_G32   = 25165824;   // 1M fp32
static constexpr size_t OFF_GWT   = 29360128;   // 16x128 fp16
static constexpr size_t OFF_GBW   = 29368320;   // 32 fp32
static constexpr size_t OFF_BIAS  = 33554432;   // 16 MiB fp16

// ------------------- prep: conv(s,kin) | convT(w*) | gw ---------------------
__global__ __launch_bounds__(256) void prep_kernel(
    const float* __restrict__ s, const float* __restrict__ kin,
    _Float16* __restrict__ s16, _Float16* __restrict__ kin16,
    const float* __restrict__ w0, const float* __restrict__ w1,
    const float* __restrict__ w2, const float* __restrict__ w3,
    const float* __restrict__ w4,
    _Float16* __restrict__ o0, _Float16* __restrict__ o1,
    _Float16* __restrict__ o2, _Float16* __restrict__ o3,
    _Float16* __restrict__ o4,
    const float* __restrict__ lng, const float* __restrict__ lnb,
    const float* __restrict__ wz, _Float16* __restrict__ gwT,
    float* __restrict__ Gbw) {
  int bid = blockIdx.x, t = threadIdx.x;
  if (bid < 1024) {  // conv role
    const float* in = (bid < 512) ? s : kin;
    _Float16* out = (bid < 512) ? s16 : kin16;
    int i = (bid & 511) * 256 + t;
    const float4* p = (const float4*)in + (size_t)i * 2;
    float4 a = p[0], b = p[1];
    h8 v;
    v[0] = (_Float16)a.x; v[1] = (_Float16)a.y; v[2] = (_Float16)a.z; v[3] = (_Float16)a.w;
    v[4] = (_Float16)b.x; v[5] = (_Float16)b.y; v[6] = (_Float16)b.z; v[7] = (_Float16)b.w;
    *(h8*)(out + (size_t)i * 8) = v;
    return;
  }
  if (bid == 2304) {  // gw prep role
    __shared__ float red[2][16][16];
    int h = t & 15, cg = t >> 4;
    float pg = 0.f, pb = 0.f;
#pragma unroll
    for (int u = 0; u < 8; ++u) {
      int c = cg * 8 + u;
      float w = wz[c * 16 + h];
      _Float16 gh = (_Float16)(lng[c] * w);
      gwT[h * 128 + c] = gh;
      pg += (float)gh;
      pb += lnb[c] * w;
    }
    red[0][h][cg] = pg; red[1][h][cg] = pb;
    __syncthreads();
    if (t < 32) {
      int hh = t & 15, which = t >> 4;
      float ssum = 0.f;
#pragma unroll
      for (int u = 0; u < 16; ++u) ssum += red[which][hh][u];
      Gbw[which * 16 + hh] = ssum;
    }
    return;
  }
  // convT role
  int r5 = bid - 1024;
  int y = r5 >> 8, tile = r5 & 255;
  const float* w; _Float16* o;
  switch (y) {
    case 0: w = w0; o = o0; break;
    case 1: w = w1; o = o1; break;
    case 2: w = w2; o = o2; break;
    case 3: w = w3; o = o3; break;
    default: w = w4; o = o4; break;
  }
  int tr = tile >> 4, tc = tile & 15;
  __shared__ _Float16 ts[64][72];
#pragma unroll
  for (int p = 0; p < 4; ++p) {
    int e = p * 1024 + t * 4;
    int r = e >> 6, c = e & 63;
    float4 v = *(const float4*)(w + (size_t)(tr * 64 + r) * 1024 + tc * 64 + c);
    h4 hv;
    hv[0] = (_Float16)v.x; hv[1] = (_Float16)v.y; hv[2] = (_Float16)v.z; hv[3] = (_Float16)v.w;
    *(h4*)&ts[r][c] = hv;
  }
  __syncthreads();
#pragma unroll
  for (int p = 0; p < 4; ++p) {
    int e = p * 1024 + t * 4;
    int n = e >> 6, k = e & 63;
    h4 hv;
#pragma unroll
    for (int u = 0; u < 4; ++u) hv[u] = ts[k + u][n];
    *(h4*)(o + (size_t)(tc * 64 + n) * 1024 + tr * 64 + k) = hv;
  }
}

// ------------- LayerNorm(z) @ wz -> bias16: register-fragment slim ----------
__global__ __launch_bounds__(256) void ln_bias_kernel(
    const float* __restrict__ z, const _Float16* __restrict__ gwT,
    const float* __restrict__ Gbw, _Float16* __restrict__ bias16) {
  int jc = blockIdx.x, i = blockIdx.y, b = blockIdx.z;
  __shared__ float outs[64][17];
  int t = threadIdx.x, wid = t >> 6, lane = t & 63;
  int lr = lane & 15, hi = lane >> 4;
  const float* zr = z + (((size_t)b * 512 + i) * 512 + (size_t)jc * 64 + wid * 16 + lr) * 128;
  h8 af[4];
  float s1 = 0.f, s2 = 0.f;
#pragma unroll
  for (int kk = 0; kk < 4; ++kk) {
    float4 v0 = *(const float4*)(zr + kk * 32 + hi * 8);
    float4 v1 = *(const float4*)(zr + kk * 32 + hi * 8 + 4);
    s1 += v0.x + v0.y + v0.z + v0.w + v1.x + v1.y + v1.z + v1.w;
    s2 += v0.x * v0.x + v0.y * v0.y + v0.z * v0.z + v0.w * v0.w +
          v1.x * v1.x + v1.y * v1.y + v1.z * v1.z + v1.w * v1.w;
    h8 a;
    a[0] = (_Float16)v0.x; a[1] = (_Float16)v0.y; a[2] = (_Float16)v0.z; a[3] = (_Float16)v0.w;
    a[4] = (_Float16)v1.x; a[5] = (_Float16)v1.y; a[6] = (_Float16)v1.z; a[7] = (_Float16)v1.w;
    af[kk] = a;
  }
  s1 += __shfl_xor(s1, 16, 64); s2 += __shfl_xor(s2, 16, 64);
  s1 += __shfl_xor(s1, 32, 64); s2 += __shfl_xor(s2, 32, 64);
  float mu = s1 * (1.0f / 128.0f);
  float var = s2 * (1.0f / 128.0f) - mu * mu;
  float rs = rsqrtf(var + 1e-5f);
  f32x4 acc = {};
#pragma unroll
  for (int kk = 0; kk < 4; ++kk) {
    h8 bf = *(const h8*)(gwT + lr * 128 + kk * 32 + hi * 8);
    acc = MFMA16(af[kk], bf, acc);
  }
  float Gl = Gbw[lr], bwl = Gbw[16 + lr];
#pragma unroll
  for (int r = 0; r < 4; ++r) {
    int src = hi * 4 + r;
    float mur = __shfl(mu, src, 64);
    float rsr = __shfl(rs, src, 64);
    outs[wid * 16 + src][lr] = rsr * (acc[r] - mur * Gl) + bwl;
  }
  __syncthreads();
  {
    int hh = t >> 4, j0w = (t & 15) * 4;
    h4 ov;
    ov[0] = (_Float16)outs[j0w + 0][hh]; ov[1] = (_Float16)outs[j0w + 1][hh];
    ov[2] = (_Float16)outs[j0w + 2][hh]; ov[3] = (_Float16)outs[j0w + 3][hh];
    *(h4*)(bias16 + (((size_t)(b * 16 + hh) * 512) + i) * 512 + (size_t)jc * 64 + j0w) = ov;
  }
}

// -------- fused 1024^3 GEMMs: 64^2 tiles (4 blocks/CU), BK=64, gload_lds ----
// mode 0: q=(s@wq+bq)/8  1: k=kin@wk  2: vT (transposed write)  3: g=sigmoid
__global__ __launch_bounds__(256) void gemm_fused(
    const _Float16* __restrict__ s16, const _Float16* __restrict__ kin16,
    const _Float16* __restrict__ wqT, const _Float16* __restrict__ wkT,
    const _Float16* __restrict__ wvT, const _Float16* __restrict__ wgT,
    const float* __restrict__ bq,
    _Float16* __restrict__ q16, _Float16* __restrict__ k16,
    _Float16* __restrict__ vT, float* __restrict__ g32) {
  int mode = blockIdx.y;
  const _Float16 *A, *BT;
  switch (mode) {
    case 0: A = s16;   BT = wqT; break;
    case 1: A = kin16; BT = wkT; break;
    case 2: A = kin16; BT = wvT; break;
    default: A = s16;  BT = wgT; break;
  }
  int bm = blockIdx.x >> 4, bn = blockIdx.x & 15;
  __shared__ _Float16 As[2][64 * 64];
  __shared__ _Float16 Bs[2][64 * 64];
  int t = threadIdx.x, wid = t >> 6, lane = t & 63;
  int wr = wid >> 1, wc = wid & 1, lr = lane & 15, hi = lane >> 4;
  const _Float16* Ab = A + (size_t)(bm * 64) * 1024;
  const _Float16* Bb = BT + (size_t)(bn * 64) * 1024;
  auto STAGE = [&](int kt, int buf) {
    int k0 = kt * 64;
#pragma unroll
    for (int p = 0; p < 2; ++p) {
      int q = (wid * 2 + p) * 64 + lane;   // 16B-unit 0..511, 8 per row
      int row = q >> 3, c16 = q & 7;
      int coff = (c16 * 16) ^ ((row & 7) << 4);
      gl_lds16(Ab + (size_t)row * 1024 + k0 + (coff >> 1),
               (char*)As[buf] + (wid * 2 + p) * 1024);
      gl_lds16(Bb + (size_t)row * 1024 + k0 + (coff >> 1),
               (char*)Bs[buf] + (wid * 2 + p) * 1024);
    }
  };
  f32x4 acc[2][2] = {};
  STAGE(0, 0);
  __syncthreads();
  for (int kt = 0; kt < 16; ++kt) {
    int buf = kt & 1;
    if (kt < 15) STAGE(kt + 1, buf ^ 1);
#pragma unroll
    for (int kk = 0; kk < 2; ++kk) {
      h8 af[2], bf[2];
#pragma unroll
      for (int mi = 0; mi < 2; ++mi) {
        int row = wr * 32 + mi * 16 + lr;
        af[mi] = *(const h8*)((char*)As[buf] + row * 128 + ((kk * 64 + hi * 16) ^ ((lr & 7) << 4)));
      }
#pragma unroll
      for (int ni = 0; ni < 2; ++ni) {
        int row = wc * 32 + ni * 16 + lr;
        bf[ni] = *(const h8*)((char*)Bs[buf] + row * 128 + ((kk * 64 + hi * 16) ^ ((lr & 7) << 4)));
      }
#pragma unroll
      for (int mi = 0; mi < 2; ++mi)
#pragma unroll
        for (int ni = 0; ni < 2; ++ni)
          acc[mi][ni] = MFMA16(af[mi], bf[ni], acc[mi][ni]);
    }
    __syncthreads();
  }

  if (mode == 2) {
    // fused transpose: tile = 64 tokens x head bn (64 d); b = bm>>3.
    _Float16 (*ts)[72] = (_Float16(*)[72])As;   // after final barrier
#pragma unroll
    for (int mi = 0; mi < 2; ++mi)
#pragma unroll
      for (int ni = 0; ni < 2; ++ni)
#pragma unroll
        for (int r = 0; r < 4; ++r) {
          int tok = wr * 32 + mi * 16 + hi * 4 + r;
          int d = wc * 32 + ni * 16 + lr;
          ts[tok][d ^ (((tok >> 3) & 7) << 3)] = (_Float16)acc[mi][ni][r];
        }
    __syncthreads();
    int b = bm >> 3;
    _Float16* vtb = vT + ((size_t)(b * 16 + bn) * 64) * 512 + (bm & 7) * 64;
#pragma unroll
    for (int p = 0; p < 2; ++p) {
      int d = p * 32 + (t >> 3), j0 = (t & 7) * 8;
      h8 v;
#pragma unroll
      for (int u = 0; u < 8; ++u) {
        int j = j0 + u;
        v[u] = ts[j][d ^ (((j >> 3) & 7) << 3)];
      }
      *(h8*)(vtb + (size_t)d * 512 + j0) = v;
    }
    return;
  }

#pragma unroll
  for (int mi = 0; mi < 2; ++mi)
#pragma unroll
    for (int ni = 0; ni < 2; ++ni)
#pragma unroll
      for (int r = 0; r < 4; ++r) {
        int row = bm * 64 + wr * 32 + mi * 16 + hi * 4 + r;
        int col = bn * 64 + wc * 32 + ni * 16 + lr;
        float v = acc[mi][ni][r];
        size_t o = (size_t)row * 1024 + col;
        switch (mode) {
          case 0: q16[o] = (_Float16)((v + bq[col]) * 0.125f); break;
          case 1: k16[o] = (_Float16)v; break;
          default: g32[o] = 1.0f / (1.0f + __expf(-v)); break;
        }
      }
}

// ----------------- fused attention: QK^T+bias -> softmax -> PV -> gate ------
__global__ __launch_bounds__(256, 2) void flash_kernel(
    const _Float16* __restrict__ q16, const _Float16* __restrict__ k16,
    const _Float16* __restrict__ vT, const _Float16* __restrict__ bias16,
    const float* __restrict__ mask, const float* __restrict__ g32,
    _Float16* __restrict__ x16) {
  int bh = blockIdx.y, b = bh >> 4, h = bh & 15;
  int i0 = blockIdx.x * 64;
  __shared__ _Float16 Kc[2][128 * 64];   // K chunks (phase1) / vT chunks (phase2)
  int t = threadIdx.x, wid = t >> 6, lane = t & 63;
  int lr = lane & 15, hi = lane >> 4;

  const _Float16* qrow = q16 + ((size_t)(b * 512) + i0 + wid * 16 + lr) * 1024 + h * 64;
  h8 qf0 = *(const h8*)(qrow + hi * 8);
  h8 qf1 = *(const h8*)(qrow + 32 + hi * 8);

  const _Float16* bbase = bias16 + ((size_t)bh * 512 + i0 + wid * 16 + lr) * 512 + hi * 4;
  const float* mbase = mask + b * 512 + hi * 4;

  auto STAGE1 = [&](int c, int buf) {
    int j0 = c * 128;
    const _Float16* kb = k16 + ((size_t)(b * 512) + j0) * 1024 + h * 64;
#pragma unroll
    for (int p = 0; p < 4; ++p) {
      int q = (wid * 4 + p) * 64 + lane;
      int row = q >> 3, c16 = q & 7;
      int coff = (c16 * 16) ^ ((row & 7) << 4);
      gl_lds16(kb + (size_t)row * 1024 + (coff >> 1),
               (char*)Kc[buf] + (wid * 4 + p) * 1024);
    }
  };

  f32x4 acc[32];
  STAGE1(0, 0);
  __syncthreads();
#pragma unroll
  for (int c = 0; c < 4; ++c) {
    int buf = c & 1;
    if (c < 3) STAGE1(c + 1, buf ^ 1);
#pragma unroll
    for (int jtl = 0; jtl < 8; ++jtl) {
      int jt = c * 8 + jtl;
      int krow = jtl * 16 + lr;
      h8 kf0 = *(const h8*)((char*)Kc[buf] + krow * 128 + ((hi * 16) ^ ((lr & 7) << 4)));
      h8 kf1 = *(const h8*)((char*)Kc[buf] + krow * 128 + ((64 + hi * 16) ^ ((lr & 7) << 4)));
      h4 bv = *(const h4*)(bbase + jt * 16);
      float4 mv = *(const float4*)(mbase + jt * 16);
      f32x4 a;
      a[0] = (float)bv[0] + (1.0f - mv.x) * -1000000.0f;
      a[1] = (float)bv[1] + (1.0f - mv.y) * -1000000.0f;
      a[2] = (float)bv[2] + (1.0f - mv.z) * -1000000.0f;
      a[3] = (float)bv[3] + (1.0f - mv.w) * -1000000.0f;
      a = MFMA16(kf0, qf0, a);
      a = MFMA16(kf1, qf1, a);
      acc[jt] = a;
    }
    __syncthreads();
  }

  float m = -3.4e38f;
#pragma unroll
  for (int jt = 0; jt < 32; ++jt)
    m = fmaxf(m, fmaxf(fmaxf(acc[jt][0], acc[jt][1]), fmaxf(acc[jt][2], acc[jt][3])));
  m = fmaxf(m, __shfl_xor(m, 16, 64));
  m = fmaxf(m, __shfl_xor(m, 32, 64));
  float ssum = 0.f;
#pragma unroll
  for (int jt = 0; jt < 32; ++jt) {
#pragma unroll
    for (int r = 0; r < 4; ++r) {
      float e = __expf(acc[jt][r] - m);
      acc[jt][r] = e;
      ssum += e;
    }
  }
  ssum += __shfl_xor(ssum, 16, 64);
  ssum += __shfl_xor(ssum, 32, 64);
  float inv = 1.0f / ssum;
  u32 pk0[32], pk1[32];
#pragma unroll
  for (int jt = 0; jt < 32; ++jt) {
    pk0[jt] = pkrtz(acc[jt][0] * inv, acc[jt][1] * inv);
    pk1[jt] = pkrtz(acc[jt][2] * inv, acc[jt][3] * inv);
  }

  auto STAGE2 = [&](int c, int buf) {
    int j0 = c * 128;
    const _Float16* vb = vT + ((size_t)bh * 64) * 512 + j0;
#pragma unroll
    for (int p = 0; p < 4; ++p) {
      int q = (wid * 4 + p) * 64 + lane;
      int row = q >> 4, c16 = q & 15;
      int coff = (c16 * 16) ^ ((row & 7) << 4);
      gl_lds16(vb + (size_t)row * 512 + (coff >> 1),
               (char*)Kc[buf] + (wid * 4 + p) * 1024);
    }
  };
  f32x4 oacc[4] = {};
  STAGE2(0, 0);
  __syncthreads();
#pragma unroll
  for (int c = 0; c < 4; ++c) {
    int buf = c & 1;
    if (c < 3) STAGE2(c + 1, buf ^ 1);
#pragma unroll
    for (int ktl = 0; ktl < 4; ++ktl) {
      int kt = c * 4 + ktl;
      int la = lr + ((hi & 1) << 5);
      int lb = la + 16;
      u32 a0 = __shfl(pk0[2 * kt], la, 64);
      u32 a1 = __shfl(pk1[2 * kt], la, 64);
      u32 b0 = __shfl(pk0[2 * kt], lb, 64);
      u32 b1 = __shfl(pk1[2 * kt], lb, 64);
      u32 c0 = __shfl(pk0[2 * kt + 1], la, 64);
      u32 c1 = __shfl(pk1[2 * kt + 1], la, 64);
      u32 d0 = __shfl(pk0[2 * kt + 1], lb, 64);
      u32 d1 = __shfl(pk1[2 * kt + 1], lb, 64);
      bool x1 = hi >= 2;
      uint4 au;
      au.x = x1 ? c0 : a0;
      au.y = x1 ? c1 : a1;
      au.z = x1 ? d0 : b0;
      au.w = x1 ? d1 : b1;
      h8 paf = __builtin_bit_cast(h8, au);
#pragma unroll
      for (int nt = 0; nt < 4; ++nt) {
        int vrow = nt * 16 + lr;
        h8 vf = *(const h8*)((char*)Kc[buf] + vrow * 256 + ((ktl * 64 + hi * 16) ^ ((lr & 7) << 4)));
        oacc[nt] = MFMA16(paf, vf, oacc[nt]);
      }
    }
    __syncthreads();
  }

  const float* gb = g32 + ((size_t)(b * 512) + i0) * 1024 + h * 64;
  _Float16* xb = x16 + ((size_t)(b * 512) + i0) * 1024 + h * 64;
#pragma unroll
  for (int nt = 0; nt < 4; ++nt)
#pragma unroll
    for (int r = 0; r < 4; ++r) {
      int il = wid * 16 + hi * 4 + r, d = nt * 16 + lr;
      size_t off = (size_t)il * 1024 + d;
      xb[off] = (_Float16)(oacc[nt][r] * gb[off]);
    }
}

// --------- out = x @ wo, 64x32 tiles (512 blocks, 2/CU), BK=64 --------------
__global__ __launch_bounds__(256) void gemm_o_kernel(
    const _Float16* __restrict__ x16, const _Float16* __restrict__ woT,
    float* __restrict__ out32) {
  int bm = blockIdx.x >> 5, bn = blockIdx.x & 31;   // 16 x 32
  __shared__ _Float16 As[2][64 * 64];
  __shared__ _Float16 Bs[2][32 * 64];
  int t = threadIdx.x, wid = t >> 6, lane = t & 63;
  int wr = wid >> 1, wc = wid & 1, lr = lane & 15, hi = lane >> 4;
  const _Float16* Ab = x16 + (size_t)(bm * 64) * 1024;
  const _Float16* Bb = woT + (size_t)(bn * 32) * 1024;
  auto STAGE = [&](int kt, int buf) {
    int k0 = kt * 64;
#pragma unroll
    for (int p = 0; p < 2; ++p) {
      int q = (wid * 2 + p) * 64 + lane;   // A: 512 units
      int row = q >> 3, c16 = q & 7;
      int coff = (c16 * 16) ^ ((row & 7) << 4);
      gl_lds16(Ab + (size_t)row * 1024 + k0 + (coff >> 1),
               (char*)As[buf] + (wid * 2 + p) * 1024);
    }
    {
      int q = t;                            // B: 256 units
      int row = q >> 3, c16 = q & 7;
      int coff = (c16 * 16) ^ ((row & 7) << 4);
      gl_lds16(Bb + (size_t)row * 1024 + k0 + (coff >> 1),
               (char*)Bs[buf] + wid * 1024);
    }
  };
  f32x4 acc[2] = {};
  STAGE(0, 0);
  __syncthreads();
  for (int kt = 0; kt < 16; ++kt) {
    int buf = kt & 1;
    if (kt < 15) STAGE(kt + 1, buf ^ 1);
#pragma unroll
    for (int kk = 0; kk < 2; ++kk) {
      h8 af[2], bf;
#pragma unroll
      for (int mi = 0; mi < 2; ++mi) {
        int row = wr * 32 + mi * 16 + lr;
        af[mi] = *(const h8*)((char*)As[buf] + row * 128 + ((kk * 64 + hi * 16) ^ ((lr & 7) << 4)));
      }
      {
        int row = wc * 16 + lr;
        bf = *(const h8*)((char*)Bs[buf] + row * 128 + ((kk * 64 + hi * 16) ^ ((lr & 7) << 4)));
      }
#pragma unroll
      for (int mi = 0; mi < 2; ++mi)
        acc[mi] = MFMA16(af[mi], bf, acc[mi]);
    }
    __syncthreads();
  }
#pragma unroll
  for (int mi = 0; mi < 2; ++mi)
#pragma unroll
    for (int r = 0; r < 4; ++r) {
      int row = bm * 64 + wr * 32 + mi * 16 + hi * 4 + r;
      int col = bn * 32 + wc * 16 + lr;
      out32[(size_t)row * 1024 + col] = acc[mi][r];
    }
}

// ----------------------------------------------------------------------------
extern "C" void kernel_launch(void* const* d_in, const int* in_sizes, int n_in,
                              void* d_out, int out_size, void* d_ws, size_t ws_size,
                              hipStream_t stream) {
  const float* s    = (const float*)d_in[0];
  const float* z    = (const float*)d_in[1];
  const float* mask = (const float*)d_in[2];
  const float* kin  = (const float*)d_in[3];
  const float* wq   = (const float*)d_in[4];
  const float* bq   = (const float*)d_in[5];
  const float* wk   = (const float*)d_in[6];
  const float* wv   = (const float*)d_in[7];
  const float* wg   = (const float*)d_in[8];
  const float* lng  = (const float*)d_in[9];
  const float* lnb  = (const float*)d_in[10];
  const float* wz   = (const float*)d_in[11];
  const float* wo   = (const float*)d_in[12];
  float* out = (float*)d_out;

  char* ws = (char*)d_ws;
  _Float16* s16   = (_Float16*)(ws + OFF_S16);
  _Float16* kin16 = (_Float16*)(ws + OFF_KIN16);
  _Float16* wqT   = (_Float16*)(ws + OFF_WQT);
  _Float16* wkT   = (_Float16*)(ws + OFF_WKT);
  _Float16* wvT   = (_Float16*)(ws + OFF_WVT);
  _Float16* wgT   = (_Float16*)(ws + OFF_WGT);
  _Float16* woT   = (_Float16*)(ws + OFF_WOT);
  _Float16* q16   = (_Float16*)(ws + OFF_Q16);
  _Float16* k16   = (_Float16*)(ws + OFF_K16);
  _Float16* vT16  = (_Float16*)(ws + OFF_VT16);
  _Float16* x16   = (_Float16*)(ws + OFF_X16);
  float* g32      = (float*)(ws + OFF_G32);
  _Float16* gwT   = (_Float16*)(ws + OFF_GWT);
  float* Gbw      = (float*)(ws + OFF_GBW);
  _Float16* bias16= (_Float16*)(ws + OFF_BIAS);

  prep_kernel<<<2305, 256, 0, stream>>>(s, kin, s16, kin16,
                                        wq, wk, wv, wg, wo,
                                        wqT, wkT, wvT, wgT, woT,
                                        lng, lnb, wz, gwT, Gbw);
  ln_bias_kernel<<<dim3(8, 512, 2), 256, 0, stream>>>(z, gwT, Gbw, bias16);
  gemm_fused<<<dim3(256, 4), 256, 0, stream>>>(s16, kin16, wqT, wkT, wvT, wgT,
                                               bq, q16, k16, vT16, g32);
  flash_kernel<<<dim3(8, 32), 256, 0, stream>>>(q16, k16, vT16, bias16,
                                                mask, g32, x16);
  gemm_o_kernel<<<512, 256, 0, stream>>>(x16, woT, out);
}